// Round 1
// 955.518 us; speedup vs baseline: 1.0870x; 1.0870x over previous
//
#include <hip/hip_runtime.h>
#include <math.h>

#define ROW_D 1024   // INV + 3*M
#define INV_D 256

typedef short bf16x8 __attribute__((ext_vector_type(8)));
typedef float f32x4 __attribute__((ext_vector_type(4)));

#define MFMA16(a,b,c) __builtin_amdgcn_mfma_f32_16x16x32_bf16((a),(b),(c),0,0,0)

__device__ __forceinline__ unsigned short f2bf(float f) {
    union { float f; unsigned int u; } x; x.f = f;
    return (unsigned short)((x.u + 0x7FFFu + ((x.u >> 16) & 1u)) >> 16);  // RNE
}
__device__ __forceinline__ float bf2f(unsigned short h) {
    union { unsigned int u; float f; } x; x.u = ((unsigned int)h) << 16;
    return x.f;
}

// ---------------------------------------------------------------------------
// Prep: bf16 weight repack into d_ws (runs every launch; ~3 us).
//  W1t[h][m] = bf16(g_w1[m][h] / std[m])            (512x256)  norm folded
//  W2t[k][h] = bf16(g_w2[h][k])                     (64x512)
//  Wcat[t*64+k][m] = bf16(W_t[m][k] * gamma[m]/16)  (192x256)  gamma,s_lin folded
//  wcb[u][v] = bf16(w_cross[u][v]), wdb likewise    (64x64)    (= B^T layout)
//  b1p[h] = g_b1[h] - sum_m mean[m]/std[m]*g_w1[m][h]
// ---------------------------------------------------------------------------
__global__ void prep_kernel(
    const float* __restrict__ g_w1, const float* __restrict__ mean_inv,
    const float* __restrict__ std_inv, const float* __restrict__ g_w2,
    const float* __restrict__ W0, const float* __restrict__ W1,
    const float* __restrict__ W2, const float* __restrict__ rms_gamma,
    const float* __restrict__ w_cross, const float* __restrict__ w_dot,
    const float* __restrict__ g_b1,
    unsigned short* __restrict__ W1t, unsigned short* __restrict__ W2t,
    unsigned short* __restrict__ Wcat, unsigned short* __restrict__ wcb,
    unsigned short* __restrict__ wdb, float* __restrict__ b1p)
{
    const int nth = gridDim.x * 256;
    for (int idx = blockIdx.x * 256 + threadIdx.x; idx < 221696; idx += nth) {
        if (idx < 131072) {
            int h = idx >> 8, m = idx & 255;
            W1t[idx] = f2bf(g_w1[m * 512 + h] / std_inv[m]);
        } else if (idx < 163840) {
            int t = idx - 131072; int k = t >> 9, h = t & 511;
            W2t[t] = f2bf(g_w2[h * 64 + k]);
        } else if (idx < 212992) {
            int t = idx - 163840; int r = t >> 8, m = t & 255;
            int tt = r >> 6, k = r & 63;
            const float* Wt = (tt == 0) ? W0 : ((tt == 1) ? W1 : W2);
            Wcat[t] = f2bf(Wt[m * 64 + k] * rms_gamma[m] * 0.0625f);
        } else if (idx < 217088) {
            int t = idx - 212992; wcb[t] = f2bf(w_cross[t]);
        } else if (idx < 221184) {
            int t = idx - 217088; wdb[t] = f2bf(w_dot[t]);
        } else {
            int h = idx - 221184;
            float s = 0.f;
            for (int m = 0; m < 256; ++m)
                s += mean_inv[m] / std_inv[m] * g_w1[m * 512 + h];
            b1p[h] = g_b1[h] - s;
        }
    }
}

// ---------------------------------------------------------------------------
// Gate: sigmoid( silu(inv @ W1' + b1') @ W2 + b2 ) -> out (fp32 gate)
// RESTRUCTURED: 64 atoms/block, 256 thr (4 waves), 3 blocks/CU.
//  - A (64x256) converted to bf16 LDS ONCE (was: 8x re-stage + re-convert).
//  - B1/B2 fragments read DIRECTLY from global (L1/L2-resident bf16 weights);
//    no B staging, no staging barriers (chi stage-2 pattern).
//  - Wave tiling 2x2 (wave wv: row-tiles (wv&1)*2+{0,1}, col-tiles (wv>>1)*2+{0,1}).
//  - acts is the only cross-wave LDS exchange -> 2 barriers/hc (17/block vs ~90).
// LDS 43008 B: As[64][264] 33792 + acts[64][72] 9216.
// ---------------------------------------------------------------------------
__global__ __launch_bounds__(256, 3) void gate_kernel(
    const float* __restrict__ emb,
    const unsigned short* __restrict__ W1t,   // [512][256] bf16
    const unsigned short* __restrict__ W2t,   // [64][512]  bf16
    const float* __restrict__ b1p,            // [512]
    const float* __restrict__ g_b2,           // [64]
    float* __restrict__ out)
{
    __shared__ __align__(16) char smem[43008];
    unsigned short* As   = (unsigned short*)smem;            // [64][264] bf16
    unsigned short* acts = (unsigned short*)(smem + 33792);  // [64][72]  bf16

    const int tid = threadIdx.x;
    const int wv = tid >> 6, ln = tid & 63;
    const int lr = ln & 15, lq = ln >> 4;
    const int wr = (wv & 1) << 1;    // row-tile base (atoms: wr*16 .. wr*16+31)
    const int wc = (wv >> 1) << 1;   // col-tile base (h/k:  wc*16 .. wc*16+31)
    const long n0 = (long)blockIdx.x * 64;

    // ---- stage A once: 64 atoms x 256 m, fp32 -> bf16 ----
#pragma unroll
    for (int i = 0; i < 16; ++i) {
        int idx = tid + i * 256;
        int atom = idx >> 6;
        int c4 = (idx & 63) << 2;
        float4 v = *(const float4*)(emb + (n0 + atom) * ROW_D + c4);
        ushort4 h;
        h.x = f2bf(v.x); h.y = f2bf(v.y); h.z = f2bf(v.z); h.w = f2bf(v.w);
        *(ushort4*)&As[atom * 264 + c4] = h;
    }
    __syncthreads();

    f32x4 acc2[2][2];
#pragma unroll
    for (int r = 0; r < 2; ++r)
#pragma unroll
        for (int c = 0; c < 2; ++c) acc2[r][c] = (f32x4){0.f, 0.f, 0.f, 0.f};

    for (int hc = 0; hc < 8; ++hc) {
        // ---- GEMM1: [64 atoms] x [64 h], K=256; B frags from global ----
        f32x4 acc1[2][2];
#pragma unroll
        for (int r = 0; r < 2; ++r)
#pragma unroll
            for (int c = 0; c < 2; ++c) acc1[r][c] = (f32x4){0.f, 0.f, 0.f, 0.f};

#pragma unroll
        for (int ks = 0; ks < 8; ++ks) {
            bf16x8 af[2], bf[2];
#pragma unroll
            for (int r = 0; r < 2; ++r)
                af[r] = *(const bf16x8*)&As[((wr + r) * 16 + lr) * 264 + ks * 32 + lq * 8];
#pragma unroll
            for (int c = 0; c < 2; ++c)
                bf[c] = *(const bf16x8*)(W1t + (hc * 64 + (wc + c) * 16 + lr) * 256
                                              + ks * 32 + lq * 8);
#pragma unroll
            for (int r = 0; r < 2; ++r)
#pragma unroll
                for (int c = 0; c < 2; ++c)
                    acc1[r][c] = MFMA16(af[r], bf[c], acc1[r][c]);
        }

        // ---- silu -> acts (each wave writes its own rows x own cols) ----
#pragma unroll
        for (int c = 0; c < 2; ++c) {
            int hl = (wc + c) * 16 + lr;
            float b = b1p[hc * 64 + hl];
#pragma unroll
            for (int r = 0; r < 2; ++r)
#pragma unroll
                for (int g = 0; g < 4; ++g) {
                    int atom = (wr + r) * 16 + lq * 4 + g;
                    float v = acc1[r][c][g] + b;
                    acts[atom * 72 + hl] = f2bf(v / (1.f + __expf(-v)));
                }
        }
        __syncthreads();   // acts fully written (col-partner wave contributes)

        // ---- GEMM2: [64 atoms] x [64 k], K=64 (this hc chunk); B2 from global ----
#pragma unroll
        for (int ks = 0; ks < 2; ++ks) {
            bf16x8 af[2], bf[2];
#pragma unroll
            for (int r = 0; r < 2; ++r)
                af[r] = *(const bf16x8*)&acts[((wr + r) * 16 + lr) * 72 + ks * 32 + lq * 8];
#pragma unroll
            for (int c = 0; c < 2; ++c)
                bf[c] = *(const bf16x8*)(W2t + ((wc + c) * 16 + lr) * 512
                                              + hc * 64 + ks * 32 + lq * 8);
#pragma unroll
            for (int r = 0; r < 2; ++r)
#pragma unroll
                for (int c = 0; c < 2; ++c)
                    acc2[r][c] = MFMA16(af[r], bf[c], acc2[r][c]);
        }
        __syncthreads();   // GEMM2 reads done -> acts writable next hc
    }

    // ---- epilogue: sigmoid -> out ----
#pragma unroll
    for (int c = 0; c < 2; ++c) {
        int k = (wc + c) * 16 + lr;
        float b2v = g_b2[k];
#pragma unroll
        for (int r = 0; r < 2; ++r)
#pragma unroll
            for (int g = 0; g < 4; ++g) {
                int atom = (wr + r) * 16 + lq * 4 + g;
                float v = acc2[r][c][g] + b2v;
                out[(n0 + atom) * 64 + k] = 1.f / (1.f + __expf(-v));
            }
    }
}

// ---------------------------------------------------------------------------
// Chi: rms(eq) -> x0/x1/x2 via MFMA [(i,atom)=96 rows x (t,k)=192 cols, K=256]
//      -> y1/y2 via MFMA [(atom,j)=96 rows x u=64 cols, K=64, B-frags from global]
//      -> cross/dot -> LN -> out *= (in-place with gate).
// 32 atoms/block, 256 thr. LDS union 41472 + x0 12544 + chi 8448 + rms = 62592.
// ---------------------------------------------------------------------------
__global__ __launch_bounds__(256, 2) void chi_kernel(
    const float* __restrict__ emb,
    const unsigned short* __restrict__ Wcat,  // [192][256] bf16
    const unsigned short* __restrict__ wcb,   // [64][64] bf16
    const unsigned short* __restrict__ wdb,   // [64][64] bf16
    const float* __restrict__ ln_w,
    const float* __restrict__ ln_b,
    float* __restrict__ out)
{
    __shared__ __align__(16) char smem[62592];
    // phase A (GEMM1):
    unsigned short* Aeq = (unsigned short*)smem;             // [96][72]  13824
    unsigned short* Bw  = (unsigned short*)(smem + 13824);   // [192][72] 27648 (end 41472)
    // phase B (x dump + stage2):  aliases A
    unsigned short* Xl1 = (unsigned short*)smem;             // [96][72] x1 as [(a,j)][v]
    unsigned short* Xl2 = (unsigned short*)(smem + 13824);   // [96][72] x2
    // phase C (y): aliases Xl
    unsigned short* y1l = (unsigned short*)smem;             // [96][72] bf16 [(a,j)][u]
    unsigned short* y2l = (unsigned short*)(smem + 13824);
    // persistent:
    unsigned short* x0l = (unsigned short*)(smem + 41472);   // [32][196] bf16 [a][k*3+i]
    float* chi_s = (float*)(smem + 54016);                   // [32][66]
    float* rms_s = (float*)(smem + 62464);                   // [32]

    const int tid = threadIdx.x;
    const int wv = tid >> 6, ln = tid & 63;
    const int lr = ln & 15, lq = ln >> 4;
    const int a_t = tid >> 3, st = tid & 7;   // staging/epilogue: 8 thr per atom
    const long n0 = (long)blockIdx.x * 32;

    f32x4 acc[6][3];
#pragma unroll
    for (int tr = 0; tr < 6; ++tr)
#pragma unroll
        for (int c = 0; c < 3; ++c) acc[tr][c] = (f32x4){0.f, 0.f, 0.f, 0.f};
    float sumsq = 0.f;

    for (int kb = 0; kb < 4; ++kb) {
        __syncthreads();
        // stage A: de-interleave eq chunk (64 m x 3 i) + accumulate sum(eq^2)
#pragma unroll
        for (int j = 0; j < 6; ++j) {
            int c = (st + 8 * j) * 4;
            float4 v = *(const float4*)(emb + (n0 + a_t) * ROW_D + INV_D + kb * 192 + c);
            sumsq += v.x * v.x + v.y * v.y + v.z * v.z + v.w * v.w;
            float vv[4] = {v.x, v.y, v.z, v.w};
#pragma unroll
            for (int e = 0; e < 4; ++e) {
                int col = c + e;
                int ml = col / 3;
                int ii = col - ml * 3;
                Aeq[(ii * 32 + a_t) * 72 + ml] = f2bf(vv[e]);
            }
        }
        // stage B: Wcat rows x 64-m chunk
#pragma unroll
        for (int i = 0; i < 6; ++i) {
            int idx = tid + i * 256;
            int row = idx >> 3, c8 = (idx & 7) << 3;
            *(uint4*)&Bw[row * 72 + c8] =
                *(const uint4*)(Wcat + row * 256 + kb * 64 + c8);
        }
        __syncthreads();
#pragma unroll
        for (int ks = 0; ks < 2; ++ks) {
            bf16x8 bfr[3];
#pragma unroll
            for (int c = 0; c < 3; ++c)
                bfr[c] = *(const bf16x8*)&Bw[((wv * 3 + c) * 16 + lr) * 72 + ks * 32 + lq * 8];
#pragma unroll
            for (int tr = 0; tr < 6; ++tr) {
                bf16x8 af = *(const bf16x8*)&Aeq[(tr * 16 + lr) * 72 + ks * 32 + lq * 8];
#pragma unroll
                for (int c = 0; c < 3; ++c)
                    acc[tr][c] = MFMA16(af, bfr[c], acc[tr][c]);
            }
        }
    }
    // rms: reduce 8 threads of each atom
    sumsq += __shfl_xor(sumsq, 1);
    sumsq += __shfl_xor(sumsq, 2);
    sumsq += __shfl_xor(sumsq, 4);
    if (st == 0) rms_s[a_t] = rsqrtf(sumsq * (1.f / 256.f) + 1e-6f);
    __syncthreads();   // rms visible; all GEMM1 reads done -> union writable

    // dump x: acc tile (tr, wv*3+c): rows (i,atom), cols (t,k). 1/rms applied here.
#pragma unroll
    for (int tr = 0; tr < 6; ++tr)
#pragma unroll
        for (int c = 0; c < 3; ++c) {
            int colg = (wv * 3 + c) * 16 + lr;
            int t = colg >> 6, k = colg & 63;
#pragma unroll
            for (int g = 0; g < 4; ++g) {
                int rowg = tr * 16 + lq * 4 + g;
                int ii = rowg >> 5, atom = rowg & 31;
                unsigned short hb = f2bf(acc[tr][c][g] * rms_s[atom]);
                if (t == 0)      x0l[atom * 196 + k * 3 + ii] = hb;
                else if (t == 1) Xl1[(atom * 3 + ii) * 72 + k] = hb;
                else             Xl2[(atom * 3 + ii) * 72 + k] = hb;
            }
        }
    __syncthreads();   // Xl visible to all waves

    // stage 2: wave -> tensor ts=wv&1 (y1:wc / y2:wd), tile-col pair cp=wv>>1
    const int ts = wv & 1, cp = wv >> 1;
    const unsigned short* Xs = ts ? Xl2 : Xl1;
    const unsigned short* Wg = ts ? wdb : wcb;
    f32x4 yacc[6][2];
#pragma unroll
    for (int tr = 0; tr < 6; ++tr)
#pragma unroll
        for (int c = 0; c < 2; ++c) yacc[tr][c] = (f32x4){0.f, 0.f, 0.f, 0.f};
#pragma unroll
    for (int ks = 0; ks < 2; ++ks) {
        bf16x8 bfr[2];
#pragma unroll
        for (int c = 0; c < 2; ++c)
            bfr[c] = *(const bf16x8*)(Wg + ((cp * 2 + c) * 16 + lr) * 64 + ks * 32 + lq * 8);
#pragma unroll
        for (int tr = 0; tr < 6; ++tr) {
            bf16x8 af = *(const bf16x8*)&Xs[(tr * 16 + lr) * 72 + ks * 32 + lq * 8];
#pragma unroll
            for (int c = 0; c < 2; ++c)
                yacc[tr][c] = MFMA16(af, bfr[c], yacc[tr][c]);
        }
    }
    __syncthreads();   // Xl reads done -> y region writable

    unsigned short* Yd = ts ? y2l : y1l;
#pragma unroll
    for (int tr = 0; tr < 6; ++tr)
#pragma unroll
        for (int c = 0; c < 2; ++c) {
            int u = (cp * 2 + c) * 16 + lr;
#pragma unroll
            for (int g = 0; g < 4; ++g) {
                int rowg = tr * 16 + lq * 4 + g;
                Yd[rowg * 72 + u] = f2bf(yacc[tr][c][g]);
            }
        }
    __syncthreads();

    // cross, dot, chi   (thread: atom a_t, u = st + 8q)
    const float CHI_SCALE = 1.0f / sqrtf(24576.0f);   // 1/(sqrt(2K)*sqrt(3K))
#pragma unroll
    for (int q = 0; q < 8; ++q) {
        int u = st + 8 * q;
        float x0a = bf2f(x0l[a_t * 196 + u * 3 + 0]);
        float x0b = bf2f(x0l[a_t * 196 + u * 3 + 1]);
        float x0c = bf2f(x0l[a_t * 196 + u * 3 + 2]);
        float y1a = bf2f(y1l[(a_t * 3 + 0) * 72 + u]);
        float y1b = bf2f(y1l[(a_t * 3 + 1) * 72 + u]);
        float y1c = bf2f(y1l[(a_t * 3 + 2) * 72 + u]);
        float y2a = bf2f(y2l[(a_t * 3 + 0) * 72 + u]);
        float y2b = bf2f(y2l[(a_t * 3 + 1) * 72 + u]);
        float y2c = bf2f(y2l[(a_t * 3 + 2) * 72 + u]);
        float c0 = x0b * y1c - x0c * y1b;
        float c1 = x0c * y1a - x0a * y1c;
        float c2 = x0a * y1b - x0b * y1a;
        chi_s[a_t * 66 + u] = (c0 * y2a + c1 * y2b + c2 * y2c) * CHI_SCALE;
    }
    __syncthreads();

    // LayerNorm over u (8 threads/atom, shfl reduce) + gate multiply
    float s = 0.f;
#pragma unroll
    for (int q = 0; q < 8; ++q) s += chi_s[a_t * 66 + st + 8 * q];
    s += __shfl_xor(s, 1); s += __shfl_xor(s, 2); s += __shfl_xor(s, 4);
    float mu = s * (1.f / 64.f);
    float vv = 0.f;
#pragma unroll
    for (int q = 0; q < 8; ++q) {
        float d = chi_s[a_t * 66 + st + 8 * q] - mu;
        vv += d * d;
    }
    vv += __shfl_xor(vv, 1); vv += __shfl_xor(vv, 2); vv += __shfl_xor(vv, 4);
    float isd = rsqrtf(vv * (1.f / 64.f) + 1e-5f);
#pragma unroll
    for (int q = 0; q < 8; ++q) {
        int u = st + 8 * q;
        float val = (chi_s[a_t * 66 + u] - mu) * isd * ln_w[u] + ln_b[u];
        long o = (n0 + a_t) * 64 + u;
        out[o] = out[o] * val;
    }
}

extern "C" void kernel_launch(void* const* d_in, const int* in_sizes, int n_in,
                              void* d_out, int out_size, void* d_ws, size_t ws_size,
                              hipStream_t stream)
{
    const float* emb       = (const float*)d_in[0];
    const float* mean_inv  = (const float*)d_in[1];
    const float* std_inv   = (const float*)d_in[2];
    const float* rms_gamma = (const float*)d_in[3];
    const float* W0        = (const float*)d_in[4];
    const float* W1        = (const float*)d_in[5];
    const float* W2        = (const float*)d_in[6];
    const float* w_cross   = (const float*)d_in[7];
    const float* w_dot     = (const float*)d_in[8];
    const float* ln_w      = (const float*)d_in[9];
    const float* ln_b      = (const float*)d_in[10];
    const float* g_w1      = (const float*)d_in[11];
    const float* g_b1      = (const float*)d_in[12];
    const float* g_w2      = (const float*)d_in[13];
    const float* g_b2      = (const float*)d_in[14];
    float* out = (float*)d_out;

    char* ws = (char*)d_ws;
    unsigned short* W1t  = (unsigned short*)(ws);            // 512*256*2 = 262144
    unsigned short* W2t  = (unsigned short*)(ws + 262144);   // 64*512*2  = 65536
    unsigned short* Wcat = (unsigned short*)(ws + 327680);   // 192*256*2 = 98304
    unsigned short* wcb  = (unsigned short*)(ws + 425984);   // 64*64*2   = 8192
    unsigned short* wdb  = (unsigned short*)(ws + 434176);   // 8192
    float*          b1p  = (float*)(ws + 442368);            // 512*4     = 2048

    const int N = in_sizes[0] / ROW_D;   // 131072

    prep_kernel<<<128, 256, 0, stream>>>(g_w1, mean_inv, std_inv, g_w2,
                                         W0, W1, W2, rms_gamma, w_cross, w_dot,
                                         g_b1, W1t, W2t, Wcat, wcb, wdb, b1p);
    gate_kernel<<<N / 64, 256, 0, stream>>>(emb, W1t, W2t, b1p, g_b2, out);
    chi_kernel<<<N / 32, 256, 0, stream>>>(emb, Wcat, wcb, wdb, ln_w, ln_b, out);
}